// Round 9
// baseline (495.736 us; speedup 1.0000x reference)
//
#include <hip/hip_runtime.h>
#include <hip/hip_bf16.h>
#include <math.h>

#define Bb 2
#define Ss 2048
#define Dd 1024
#define Hh 16
#define DKk 64
#define BSn (Bb*Ss)

typedef unsigned short u16;
typedef __attribute__((ext_vector_type(8))) short frag_ab;   // 8 bf16
typedef __attribute__((ext_vector_type(4))) float frag_cd;   // 4 f32

static __device__ __forceinline__ u16 f2bf(float x) {
    __hip_bfloat16 h = __float2bfloat16(x);
    return *reinterpret_cast<u16*>(&h);
}

// ---------------------------------------------------------------------------
// One-shot convert: q,k,v fp32 -> bf16; W* fp32 [k][n] -> bf16 transposed [n][k].
// ---------------------------------------------------------------------------
__global__ __launch_bounds__(256)
void convert_kernel(const float* __restrict__ q, const float* __restrict__ k,
                    const float* __restrict__ v,
                    const float* __restrict__ Wq, const float* __restrict__ Wk,
                    const float* __restrict__ Wv, const float* __restrict__ Wo,
                    u16* __restrict__ qb, u16* __restrict__ kb, u16* __restrict__ vb,
                    u16* __restrict__ wqt, u16* __restrict__ wkt,
                    u16* __restrict__ wvt, u16* __restrict__ wot)
{
    __shared__ u16 T[64 * 80];
    const int tid = threadIdx.x;
    const int bid = blockIdx.x;
    if (bid < 3072) {
        int t = bid >> 10;
        const float* src = (t == 0) ? q : (t == 1) ? k : v;
        u16* dst = (t == 0) ? qb : (t == 1) ? kb : vb;
        size_t base = (size_t)(bid & 1023) * 4096;
#pragma unroll
        for (int i = 0; i < 4; ++i) {
            size_t e = base + (size_t)(tid + i * 256) * 4;
            float4 xv = *(const float4*)(src + e);
            ushort4 o;
            o.x = f2bf(xv.x); o.y = f2bf(xv.y); o.z = f2bf(xv.z); o.w = f2bf(xv.w);
            *(ushort4*)(dst + e) = o;
        }
    } else {
        int wbid = bid - 3072;
        int w = wbid >> 8;
        const float* src = (w == 0) ? Wq : (w == 1) ? Wk : (w == 2) ? Wv : Wo;
        u16* dst = (w == 0) ? wqt : (w == 1) ? wkt : (w == 2) ? wvt : wot;
        int t = wbid & 255;
        int k0 = (t >> 4) * 64, nt0 = (t & 15) * 64;
#pragma unroll
        for (int i = 0; i < 4; ++i) {
            int f = tid + i * 256;
            int kk = f >> 4, nn = (f & 15) * 4;
            float4 xv = *(const float4*)(src + (size_t)(k0 + kk) * Dd + nt0 + nn);
            T[(nn + 0) * 80 + kk] = f2bf(xv.x);
            T[(nn + 1) * 80 + kk] = f2bf(xv.y);
            T[(nn + 2) * 80 + kk] = f2bf(xv.z);
            T[(nn + 3) * 80 + kk] = f2bf(xv.w);
        }
        __syncthreads();
#pragma unroll
        for (int i = 0; i < 2; ++i) {
            int g = tid + i * 256;
            int nn = g >> 3, k8 = (g & 7) * 8;
            *(uint4*)(dst + (size_t)(nt0 + nn) * Dd + k0 + k8) =
                *(const uint4*)&T[nn * 80 + k8];
        }
    }
}

// ---------------------------------------------------------------------------
// bf16 MFMA GEMM — R5 tile (128x64, BK=64, no-spill) + two additions:
//  * z-grid QKV fusion (fused=1: z=0 Q rope+1/8, z=1 K rope, z=2 V^T)
//  * VGPR prefetch of next K-tile issued before compute (hides HBM latency)
// fused=0: single problem, fp32 out (final projection).
// ---------------------------------------------------------------------------
__global__ __launch_bounds__(256)
void gemm_bf16(const u16* __restrict__ X0, const u16* __restrict__ X1,
               const u16* __restrict__ X2,
               const u16* __restrict__ W0, const u16* __restrict__ W1,
               const u16* __restrict__ W2,
               const float* __restrict__ b0, const float* __restrict__ b1,
               const float* __restrict__ b2,
               u16* __restrict__ O0, u16* __restrict__ O1, u16* __restrict__ O2,
               float* __restrict__ OutF, int fused)
{
    __shared__ u16 As[128 * 72];
    __shared__ u16 Bs[64 * 72];

    const int tid = threadIdx.x;
    const int wv = tid >> 6, lane = tid & 63, l16 = lane & 15, quad = lane >> 4;
    const int n0 = blockIdx.x * 64, m0 = blockIdx.y * 128;
    const int z = blockIdx.z;

    const u16* X      = fused ? ((z == 0) ? X0 : (z == 1) ? X1 : X2) : X0;
    const u16* Wt     = fused ? ((z == 0) ? W0 : (z == 1) ? W1 : W2) : W0;
    const float* bias = fused ? ((z == 0) ? b0 : (z == 1) ? b1 : b2) : b0;
    u16* OutB         = (z == 0) ? O0 : (z == 1) ? O1 : O2;
    const int mode    = fused ? ((z == 0) ? 1 : (z == 1) ? 3 : 2) : 0;

    const int r8 = tid >> 3, c8 = (tid & 7) * 8;

    frag_cd acc[2][4];
#pragma unroll
    for (int ms = 0; ms < 2; ++ms)
#pragma unroll
        for (int n = 0; n < 4; ++n) acc[ms][n] = (frag_cd){0.f, 0.f, 0.f, 0.f};

    uint4 av[4], bvv[2];
#pragma unroll
    for (int p = 0; p < 4; ++p)
        av[p] = *(const uint4*)&X[(size_t)(m0 + r8 + p * 32) * Dd + c8];
#pragma unroll
    for (int p = 0; p < 2; ++p)
        bvv[p] = *(const uint4*)&Wt[(size_t)(n0 + r8 + p * 32) * Dd + c8];

    for (int k0 = 0; k0 < Dd; k0 += 64) {
        __syncthreads();   // prev-iter LDS readers done
#pragma unroll
        for (int p = 0; p < 4; ++p)
            *(uint4*)&As[(r8 + p * 32) * 72 + c8] = av[p];
#pragma unroll
        for (int p = 0; p < 2; ++p)
            *(uint4*)&Bs[(r8 + p * 32) * 72 + c8] = bvv[p];
        __syncthreads();

        // prefetch next K-tile while this one computes
        const int kn = (k0 + 64 < Dd) ? k0 + 64 : k0;
#pragma unroll
        for (int p = 0; p < 4; ++p)
            av[p] = *(const uint4*)&X[(size_t)(m0 + r8 + p * 32) * Dd + kn + c8];
#pragma unroll
        for (int p = 0; p < 2; ++p)
            bvv[p] = *(const uint4*)&Wt[(size_t)(n0 + r8 + p * 32) * Dd + kn + c8];

#pragma unroll
        for (int ks = 0; ks < 2; ++ks) {
            frag_ab a0 = *(const frag_ab*)&As[(wv * 32 + l16) * 72 + ks * 32 + quad * 8];
            frag_ab a1 = *(const frag_ab*)&As[(wv * 32 + 16 + l16) * 72 + ks * 32 + quad * 8];
#pragma unroll
            for (int n = 0; n < 4; ++n) {
                frag_ab b = *(const frag_ab*)&Bs[(n * 16 + l16) * 72 + ks * 32 + quad * 8];
                acc[0][n] = __builtin_amdgcn_mfma_f32_16x16x32_bf16(a0, b, acc[0][n], 0, 0, 0);
                acc[1][n] = __builtin_amdgcn_mfma_f32_16x16x32_bf16(a1, b, acc[1][n], 0, 0, 0);
            }
        }
    }

    float bv4[4];
#pragma unroll
    for (int n = 0; n < 4; ++n) bv4[n] = bias[n0 + n * 16 + l16];

    if (mode == 0) {
#pragma unroll
        for (int ms = 0; ms < 2; ++ms)
#pragma unroll
            for (int r = 0; r < 4; ++r) {
                int row = m0 + wv * 32 + ms * 16 + quad * 4 + r;
#pragma unroll
                for (int n = 0; n < 4; ++n)
                    OutF[(size_t)row * Dd + n0 + n * 16 + l16] = acc[ms][n][r] + bv4[n];
            }
    } else if (mode == 2) {
        const int h = n0 >> 6;
        const int b = m0 >> 11;
#pragma unroll
        for (int ms = 0; ms < 2; ++ms) {
            int sbase = (m0 & (Ss - 1)) + wv * 32 + ms * 16 + quad * 4;
#pragma unroll
            for (int n = 0; n < 4; ++n) {
                int d = n * 16 + l16;
                ushort4 o;
                o.x = f2bf(acc[ms][n][0] + bv4[n]);
                o.y = f2bf(acc[ms][n][1] + bv4[n]);
                o.z = f2bf(acc[ms][n][2] + bv4[n]);
                o.w = f2bf(acc[ms][n][3] + bv4[n]);
                *(ushort4*)&OutB[(((size_t)b * Hh + h) * DKk + d) * Ss + sbase] = o;
            }
        }
    } else {
        const int h = n0 >> 6;
        const float lg = 0.28782313662425575f;  // ln(10000)/32
        const float sc = (mode == 1) ? 0.125f : 1.0f;
#pragma unroll
        for (int ms = 0; ms < 2; ++ms)
#pragma unroll
            for (int r = 0; r < 4; ++r) {
                int row = m0 + wv * 32 + ms * 16 + quad * 4 + r;
                int b = row >> 11, s = row & (Ss - 1);
                u16* orow = OutB + (((size_t)b * Hh + h) * Ss + s) * DKk;
#pragma unroll
                for (int n = 0; n < 2; ++n) {
                    int j = n * 16 + l16;
                    float ang = (float)s * __expf(-(float)j * lg);
                    float cv = cosf(ang), sv = sinf(ang);
                    float lo = acc[ms][n][r] + bv4[n];
                    float hi = acc[ms][n + 2][r] + bv4[n + 2];
                    orow[j]      = f2bf((lo * cv - hi * sv) * sc);
                    orow[j + 32] = f2bf((hi * cv + lo * sv) * sc);
                }
            }
    }
}

// ---------------------------------------------------------------------------
// MFMA flash attention: 64-q-tile x 128-k-tile, paired q-tiles (px, 31-px)
// -> constant 17 k-iters/block. VGPR staging, padded LDS, register softmax.
// (R7's attention — correctness proven in the R7 run.)
// ---------------------------------------------------------------------------
__global__ __launch_bounds__(256)
void attn_mfma(const u16* __restrict__ Q, const u16* __restrict__ K,
               const u16* __restrict__ Vt, u16* __restrict__ Aout)
{
    __shared__ u16 Qs[64 * 72];          //  [qrow][dk]
    __shared__ u16 Ks[128 * 72];         //  [kcol][dk]
    __shared__ u16 Vs[64 * 136];         //  [d][j 0..127]
    __shared__ u16 Ps[4 * 16 * 136];     //  per-wave [qrow][j]

    const int tid = threadIdx.x;
    const int wv = tid >> 6, lane = tid & 63, l16 = lane & 15, quad = lane >> 4;
    const int px = blockIdx.x, bh = blockIdx.y;
    const size_t qkbase = (size_t)bh * Ss * DKk;
    const size_t vbase  = (size_t)bh * DKk * Ss;
    const int b = bh >> 4, h = bh & 15;

#pragma unroll
    for (int half = 0; half < 2; ++half) {
        const int t = half ? (31 - px) : px;
        const int q0 = t * 64;

        uint4 qv[2];
#pragma unroll
        for (int p = 0; p < 2; ++p) {
            int idx = tid + p * 256;
            int row = idx >> 3, slot = idx & 7;
            qv[p] = *(const uint4*)&Q[qkbase + (size_t)(q0 + row) * DKk + slot * 8];
        }
        __syncthreads();   // prev q-tile readers done
#pragma unroll
        for (int p = 0; p < 2; ++p) {
            int idx = tid + p * 256;
            int row = idx >> 3, slot = idx & 7;
            *(uint4*)&Qs[row * 72 + slot * 8] = qv[p];
        }

        float m_r[4], l_r[4];
#pragma unroll
        for (int r = 0; r < 4; ++r) { m_r[r] = -3.0e38f; l_r[r] = 0.f; }
        frag_cd of[4];
#pragma unroll
        for (int n = 0; n < 4; ++n) of[n] = (frag_cd){0.f, 0.f, 0.f, 0.f};

        const int nkt = (t >> 1) + 1;
        for (int kt = 0; kt < nkt; ++kt) {
            const int k0 = kt * 128;
            uint4 kv4[4], vv4[4];
#pragma unroll
            for (int p = 0; p < 4; ++p) {
                int idx = tid + p * 256;
                int kr = idx >> 3, ks8 = idx & 7;          // K: 128 rows x 8 slots
                kv4[p] = *(const uint4*)&K[qkbase + (size_t)(k0 + kr) * DKk + ks8 * 8];
                int vr = idx >> 4, vs8 = idx & 15;         // V: 64 rows x 16 slots
                vv4[p] = *(const uint4*)&Vt[vbase + (size_t)vr * Ss + k0 + vs8 * 8];
            }
            __syncthreads();   // prev-iter LDS readers done (also covers Qs w->r)
#pragma unroll
            for (int p = 0; p < 4; ++p) {
                int idx = tid + p * 256;
                int kr = idx >> 3, ks8 = idx & 7;
                *(uint4*)&Ks[kr * 72 + ks8 * 8] = kv4[p];
                int vr = idx >> 4, vs8 = idx & 15;
                *(uint4*)&Vs[vr * 136 + vs8 * 8] = vv4[p];
            }
            __syncthreads();

            // S = (Q/8) K^T over 128 key cols (8 n-subtiles)
            frag_cd sf[8];
#pragma unroll
            for (int n = 0; n < 8; ++n) sf[n] = (frag_cd){0.f, 0.f, 0.f, 0.f};
#pragma unroll
            for (int h2 = 0; h2 < 2; ++h2) {
                frag_ab qa = *(const frag_ab*)&Qs[(wv * 16 + l16) * 72 + h2 * 32 + quad * 8];
#pragma unroll
                for (int n = 0; n < 8; ++n) {
                    frag_ab kf = *(const frag_ab*)&Ks[(n * 16 + l16) * 72 + h2 * 32 + quad * 8];
                    sf[n] = __builtin_amdgcn_mfma_f32_16x16x32_bf16(qa, kf, sf[n], 0, 0, 0);
                }
            }

            if (kt == nkt - 1) {   // causal mask on the diagonal 128-tile
#pragma unroll
                for (int r = 0; r < 4; ++r) {
                    int qi = q0 + wv * 16 + quad * 4 + r;
#pragma unroll
                    for (int n = 0; n < 8; ++n) {
                        int ki = k0 + n * 16 + l16;
                        if (ki > qi) sf[n][r] = -1.0e30f;
                    }
                }
            }

            // online softmax in registers
            float alpha[4];
#pragma unroll
            for (int r = 0; r < 4; ++r) {
                float mx = m_r[r];
#pragma unroll
                for (int n = 0; n < 8; ++n) mx = fmaxf(mx, sf[n][r]);
#pragma unroll
                for (int off = 1; off < 16; off <<= 1) mx = fmaxf(mx, __shfl_xor(mx, off));
                float a = __expf(m_r[r] - mx);
                m_r[r] = mx;
                float sum = 0.f;
#pragma unroll
                for (int n = 0; n < 8; ++n) {
                    float p = __expf(sf[n][r] - mx);
                    sf[n][r] = p;
                    sum += p;
                }
#pragma unroll
                for (int off = 1; off < 16; off <<= 1) sum += __shfl_xor(sum, off);
                l_r[r] = l_r[r] * a + sum;
                alpha[r] = a;
            }
#pragma unroll
            for (int n = 0; n < 4; ++n)
#pragma unroll
                for (int r = 0; r < 4; ++r) of[n][r] *= alpha[r];

            // P (C-layout) -> wave-private LDS strip (A-layout rows)
#pragma unroll
            for (int n = 0; n < 8; ++n)
#pragma unroll
                for (int r = 0; r < 4; ++r)
                    Ps[wv * 2176 + (quad * 4 + r) * 136 + n * 16 + l16] = f2bf(sf[n][r]);
            __threadfence_block();

            // O += P @ V  (j = 128 in 4 ks-steps of 32)
#pragma unroll
            for (int ks = 0; ks < 4; ++ks) {
                frag_ab pa = *(const frag_ab*)&Ps[wv * 2176 + l16 * 136 + ks * 32 + quad * 8];
#pragma unroll
                for (int n = 0; n < 4; ++n) {
                    frag_ab vf = *(const frag_ab*)&Vs[(n * 16 + l16) * 136 + ks * 32 + quad * 8];
                    of[n] = __builtin_amdgcn_mfma_f32_16x16x32_bf16(pa, vf, of[n], 0, 0, 0);
                }
            }
        }

#pragma unroll
        for (int r = 0; r < 4; ++r) {
            float inv = 1.f / l_r[r];
            int row = q0 + wv * 16 + quad * 4 + r;
            u16* orow = Aout + ((size_t)b * Ss + row) * Dd + h * DKk;
#pragma unroll
            for (int n = 0; n < 4; ++n) orow[n * 16 + l16] = f2bf(of[n][r] * inv);
        }
    }
}

extern "C" void kernel_launch(void* const* d_in, const int* in_sizes, int n_in,
                              void* d_out, int out_size, void* d_ws, size_t ws_size,
                              hipStream_t stream) {
    (void)in_sizes; (void)n_in; (void)out_size;
    const float* q  = (const float*)d_in[0];
    const float* k  = (const float*)d_in[1];
    const float* v  = (const float*)d_in[2];
    // d_in[3] = mask (tril causal) -- enforced analytically in attn_mfma
    const float* Wq = (const float*)d_in[4];
    const float* bq = (const float*)d_in[5];
    const float* Wk = (const float*)d_in[6];
    const float* bk = (const float*)d_in[7];
    const float* Wv = (const float*)d_in[8];
    const float* bv = (const float*)d_in[9];
    const float* Wo = (const float*)d_in[10];
    const float* bo = (const float*)d_in[11];
    float* out = (float*)d_out;

    const size_t E = (size_t)Bb * Ss * Dd;     // 4,194,304
    const size_t Wn = (size_t)Dd * Dd;         // 1,048,576
    const size_t need = (7 * E + 4 * Wn) * sizeof(u16);   // 64 MiB
    if (ws_size < need) return;
    u16* qa  = (u16*)d_ws;
    u16* ka  = qa + E;
    u16* va  = ka + E;
    u16* wqt = va + E;
    u16* wkt = wqt + Wn;
    u16* wvt = wkt + Wn;
    u16* wot = wvt + Wn;
    u16* Qh  = wot + Wn;
    u16* Kh  = Qh + E;
    u16* Vth = Kh + E;
    u16* Abf = Vth + E;

    convert_kernel<<<4096, 256, 0, stream>>>(q, k, v, Wq, Wk, Wv, Wo,
                                             qa, ka, va, wqt, wkt, wvt, wot);
    gemm_bf16<<<dim3(Dd / 64, BSn / 128, 3), 256, 0, stream>>>(
        qa, ka, va, wqt, wkt, wvt, bq, bk, bv, Qh, Kh, Vth, nullptr, 1);
    attn_mfma<<<dim3(16, Bb * Hh), 256, 0, stream>>>(Qh, Kh, Vth, Abf);
    gemm_bf16<<<dim3(Dd / 64, BSn / 128, 1), 256, 0, stream>>>(
        Abf, nullptr, nullptr, wot, nullptr, nullptr, bo, nullptr, nullptr,
        nullptr, nullptr, nullptr, out, 0);
}

// Round 10
// 352.358 us; speedup vs baseline: 1.4069x; 1.4069x over previous
//
#include <hip/hip_runtime.h>
#include <hip/hip_bf16.h>
#include <math.h>

#define Bb 2
#define Ss 2048
#define Dd 1024
#define Hh 16
#define DKk 64
#define BSn (Bb*Ss)

typedef unsigned short u16;
typedef __attribute__((ext_vector_type(8))) short frag_ab;   // 8 bf16
typedef __attribute__((ext_vector_type(4))) float frag_cd;   // 4 f32

static __device__ __forceinline__ u16 f2bf(float x) {
    __hip_bfloat16 h = __float2bfloat16(x);
    return *reinterpret_cast<u16*>(&h);
}

// ---------------------------------------------------------------------------
// One-shot convert: q,k,v fp32 -> bf16; W* fp32 [k][n] -> bf16 transposed [n][k].
// ---------------------------------------------------------------------------
__global__ __launch_bounds__(256)
void convert_kernel(const float* __restrict__ q, const float* __restrict__ k,
                    const float* __restrict__ v,
                    const float* __restrict__ Wq, const float* __restrict__ Wk,
                    const float* __restrict__ Wv, const float* __restrict__ Wo,
                    u16* __restrict__ qb, u16* __restrict__ kb, u16* __restrict__ vb,
                    u16* __restrict__ wqt, u16* __restrict__ wkt,
                    u16* __restrict__ wvt, u16* __restrict__ wot)
{
    __shared__ u16 T[64 * 80];
    const int tid = threadIdx.x;
    const int bid = blockIdx.x;
    if (bid < 3072) {
        int t = bid >> 10;
        const float* src = (t == 0) ? q : (t == 1) ? k : v;
        u16* dst = (t == 0) ? qb : (t == 1) ? kb : vb;
        size_t base = (size_t)(bid & 1023) * 4096;
#pragma unroll
        for (int i = 0; i < 4; ++i) {
            size_t e = base + (size_t)(tid + i * 256) * 4;
            float4 xv = *(const float4*)(src + e);
            ushort4 o;
            o.x = f2bf(xv.x); o.y = f2bf(xv.y); o.z = f2bf(xv.z); o.w = f2bf(xv.w);
            *(ushort4*)(dst + e) = o;
        }
    } else {
        int wbid = bid - 3072;
        int w = wbid >> 8;
        const float* src = (w == 0) ? Wq : (w == 1) ? Wk : (w == 2) ? Wv : Wo;
        u16* dst = (w == 0) ? wqt : (w == 1) ? wkt : (w == 2) ? wvt : wot;
        int t = wbid & 255;
        int k0 = (t >> 4) * 64, nt0 = (t & 15) * 64;
#pragma unroll
        for (int i = 0; i < 4; ++i) {
            int f = tid + i * 256;
            int kk = f >> 4, nn = (f & 15) * 4;
            float4 xv = *(const float4*)(src + (size_t)(k0 + kk) * Dd + nt0 + nn);
            T[(nn + 0) * 80 + kk] = f2bf(xv.x);
            T[(nn + 1) * 80 + kk] = f2bf(xv.y);
            T[(nn + 2) * 80 + kk] = f2bf(xv.z);
            T[(nn + 3) * 80 + kk] = f2bf(xv.w);
        }
        __syncthreads();
#pragma unroll
        for (int i = 0; i < 2; ++i) {
            int g = tid + i * 256;
            int nn = g >> 3, k8 = (g & 7) * 8;
            *(uint4*)(dst + (size_t)(nt0 + nn) * Dd + k0 + k8) =
                *(const uint4*)&T[nn * 80 + k8];
        }
    }
}

// ---------------------------------------------------------------------------
// bf16 MFMA GEMM — R5 body VERBATIM (128x64 tile, BK=64, direct global->LDS
// staging, nothing held across barriers => no spills, 44-52 VGPR).
// Only addition: z-grid QKV fusion (uniform pointer select, fused=1).
// R6/R7/R9 lesson: prefetch/bigger tiles => scratch spill flood. Don't.
// ---------------------------------------------------------------------------
__global__ __launch_bounds__(256)
void gemm_bf16(const u16* __restrict__ X0, const u16* __restrict__ X1,
               const u16* __restrict__ X2,
               const u16* __restrict__ W0, const u16* __restrict__ W1,
               const u16* __restrict__ W2,
               const float* __restrict__ b0, const float* __restrict__ b1,
               const float* __restrict__ b2,
               u16* __restrict__ O0, u16* __restrict__ O1, u16* __restrict__ O2,
               float* __restrict__ OutF, int fused)
{
    __shared__ u16 As[128 * 72];
    __shared__ u16 Bs[64 * 72];

    const int tid = threadIdx.x;
    const int wv = tid >> 6, lane = tid & 63, l16 = lane & 15, quad = lane >> 4;
    const int n0 = blockIdx.x * 64, m0 = blockIdx.y * 128;
    const int z = blockIdx.z;

    const u16* X      = fused ? ((z == 0) ? X0 : (z == 1) ? X1 : X2) : X0;
    const u16* Wt     = fused ? ((z == 0) ? W0 : (z == 1) ? W1 : W2) : W0;
    const float* bias = fused ? ((z == 0) ? b0 : (z == 1) ? b1 : b2) : b0;
    u16* OutB         = (z == 0) ? O0 : (z == 1) ? O1 : O2;
    const int mode    = fused ? ((z == 0) ? 1 : (z == 1) ? 3 : 2) : 0;

    frag_cd acc[2][4];
#pragma unroll
    for (int ms = 0; ms < 2; ++ms)
#pragma unroll
        for (int n = 0; n < 4; ++n) acc[ms][n] = (frag_cd){0.f, 0.f, 0.f, 0.f};

    for (int k0 = 0; k0 < Dd; k0 += 64) {
        __syncthreads();   // prev-iter LDS readers done
#pragma unroll
        for (int p = 0; p < 4; ++p) {
            int idx = tid + p * 256;
            int row = idx >> 3, slot = idx & 7;
            *(uint4*)&As[row * 72 + slot * 8] =
                *(const uint4*)&X[(size_t)(m0 + row) * Dd + k0 + slot * 8];
        }
#pragma unroll
        for (int p = 0; p < 2; ++p) {
            int idx = tid + p * 256;
            int row = idx >> 3, slot = idx & 7;
            *(uint4*)&Bs[row * 72 + slot * 8] =
                *(const uint4*)&Wt[(size_t)(n0 + row) * Dd + k0 + slot * 8];
        }
        __syncthreads();
#pragma unroll
        for (int ks = 0; ks < 2; ++ks) {
            frag_ab a0 = *(const frag_ab*)&As[(wv * 32 + l16) * 72 + ks * 32 + quad * 8];
            frag_ab a1 = *(const frag_ab*)&As[(wv * 32 + 16 + l16) * 72 + ks * 32 + quad * 8];
#pragma unroll
            for (int n = 0; n < 4; ++n) {
                frag_ab b = *(const frag_ab*)&Bs[(n * 16 + l16) * 72 + ks * 32 + quad * 8];
                acc[0][n] = __builtin_amdgcn_mfma_f32_16x16x32_bf16(a0, b, acc[0][n], 0, 0, 0);
                acc[1][n] = __builtin_amdgcn_mfma_f32_16x16x32_bf16(a1, b, acc[1][n], 0, 0, 0);
            }
        }
    }

    float bv4[4];
#pragma unroll
    for (int n = 0; n < 4; ++n) bv4[n] = bias[n0 + n * 16 + l16];

    if (mode == 0) {
#pragma unroll
        for (int ms = 0; ms < 2; ++ms)
#pragma unroll
            for (int r = 0; r < 4; ++r) {
                int row = m0 + wv * 32 + ms * 16 + quad * 4 + r;
#pragma unroll
                for (int n = 0; n < 4; ++n)
                    OutF[(size_t)row * Dd + n0 + n * 16 + l16] = acc[ms][n][r] + bv4[n];
            }
    } else if (mode == 2) {
        const int h = n0 >> 6;
        const int b = m0 >> 11;
#pragma unroll
        for (int ms = 0; ms < 2; ++ms) {
            int sbase = (m0 & (Ss - 1)) + wv * 32 + ms * 16 + quad * 4;
#pragma unroll
            for (int n = 0; n < 4; ++n) {
                int d = n * 16 + l16;
                ushort4 o;
                o.x = f2bf(acc[ms][n][0] + bv4[n]);
                o.y = f2bf(acc[ms][n][1] + bv4[n]);
                o.z = f2bf(acc[ms][n][2] + bv4[n]);
                o.w = f2bf(acc[ms][n][3] + bv4[n]);
                *(ushort4*)&OutB[(((size_t)b * Hh + h) * DKk + d) * Ss + sbase] = o;
            }
        }
    } else {
        const int h = n0 >> 6;
        const float lg = 0.28782313662425575f;  // ln(10000)/32
        const float sc = (mode == 1) ? 0.125f : 1.0f;
#pragma unroll
        for (int ms = 0; ms < 2; ++ms)
#pragma unroll
            for (int r = 0; r < 4; ++r) {
                int row = m0 + wv * 32 + ms * 16 + quad * 4 + r;
                int b = row >> 11, s = row & (Ss - 1);
                u16* orow = OutB + (((size_t)b * Hh + h) * Ss + s) * DKk;
#pragma unroll
                for (int n = 0; n < 2; ++n) {
                    int j = n * 16 + l16;
                    float ang = (float)s * __expf(-(float)j * lg);
                    float cv = cosf(ang), sv = sinf(ang);
                    float lo = acc[ms][n][r] + bv4[n];
                    float hi = acc[ms][n + 2][r] + bv4[n + 2];
                    orow[j]      = f2bf((lo * cv - hi * sv) * sc);
                    orow[j + 32] = f2bf((hi * cv + lo * sv) * sc);
                }
            }
    }
}

// ---------------------------------------------------------------------------
// MFMA flash attention — R8-measured version VERBATIM (104 µs):
// 64x64 tiles, paired q-tiles (px, 31-px) -> constant 33 iters/block,
// register online-softmax, wave-private P strip.
// ---------------------------------------------------------------------------
__global__ __launch_bounds__(256)
void attn_mfma(const u16* __restrict__ Q, const u16* __restrict__ K,
               const u16* __restrict__ Vt, u16* __restrict__ Aout)
{
    __shared__ u16 Qs[64 * 72];
    __shared__ u16 Ks[64 * 72];
    __shared__ u16 Vs[64 * 72];
    __shared__ u16 Ps[4 * 16 * 72];

    const int tid = threadIdx.x;
    const int wv = tid >> 6;
    const int lane = tid & 63;
    const int l16 = lane & 15;
    const int quad = lane >> 4;

    const int px = blockIdx.x, bh = blockIdx.y;
    const size_t qkbase = (size_t)bh * Ss * DKk;
    const size_t vbase  = (size_t)bh * DKk * Ss;
    const int b = bh >> 4, h = bh & 15;

#pragma unroll
    for (int half = 0; half < 2; ++half) {
        const int qb = half ? (31 - px) : px;
        const int q0 = qb * 64;

        __syncthreads();   // prev half's Qs readers done before restage
#pragma unroll
        for (int rep = 0; rep < 2; ++rep) {
            int g = tid + rep * 256;
            int row = g >> 3, c8 = (g & 7) * 8;
            *(uint4*)&Qs[row * 72 + c8] =
                *(const uint4*)&Q[qkbase + (size_t)(q0 + row) * DKk + c8];
        }

        float m_r[4], l_r[4];
#pragma unroll
        for (int r = 0; r < 4; ++r) { m_r[r] = -3.0e38f; l_r[r] = 0.f; }
        frag_cd of[4];
#pragma unroll
        for (int n = 0; n < 4; ++n) of[n] = (frag_cd){0.f, 0.f, 0.f, 0.f};

        for (int kb = 0; kb <= qb; ++kb) {
            const int k0 = kb * 64;
            __syncthreads();   // prev-iter Ks/Vs/Ps readers done (also Qs w->r)
#pragma unroll
            for (int rep = 0; rep < 2; ++rep) {
                int g = tid + rep * 256;
                int row = g >> 3, c8 = (g & 7) * 8;
                *(uint4*)&Ks[row * 72 + c8] =
                    *(const uint4*)&K[qkbase + (size_t)(k0 + row) * DKk + c8];
                *(uint4*)&Vs[row * 72 + c8] =
                    *(const uint4*)&Vt[vbase + (size_t)row * Ss + k0 + c8];
            }
            __syncthreads();

            frag_cd sf[4];
#pragma unroll
            for (int n = 0; n < 4; ++n) sf[n] = (frag_cd){0.f, 0.f, 0.f, 0.f};
#pragma unroll
            for (int h2 = 0; h2 < 2; ++h2) {
                frag_ab qa = *(const frag_ab*)&Qs[(wv * 16 + l16) * 72 + h2 * 32 + quad * 8];
#pragma unroll
                for (int n = 0; n < 4; ++n) {
                    frag_ab kf = *(const frag_ab*)&Ks[(n * 16 + l16) * 72 + h2 * 32 + quad * 8];
                    sf[n] = __builtin_amdgcn_mfma_f32_16x16x32_bf16(qa, kf, sf[n], 0, 0, 0);
                }
            }

            if (kb == qb) {
#pragma unroll
                for (int r = 0; r < 4; ++r) {
                    int qi = wv * 16 + quad * 4 + r;
#pragma unroll
                    for (int n = 0; n < 4; ++n)
                        if (n * 16 + l16 > qi) sf[n][r] = -1.0e30f;
                }
            }

            float alpha[4];
#pragma unroll
            for (int r = 0; r < 4; ++r) {
                float mx = m_r[r];
#pragma unroll
                for (int n = 0; n < 4; ++n) mx = fmaxf(mx, sf[n][r]);
#pragma unroll
                for (int off = 1; off < 16; off <<= 1) mx = fmaxf(mx, __shfl_xor(mx, off));
                float a = __expf(m_r[r] - mx);
                m_r[r] = mx;
                float sum = 0.f;
#pragma unroll
                for (int n = 0; n < 4; ++n) {
                    float p = __expf(sf[n][r] - mx);
                    sf[n][r] = p;
                    sum += p;
                }
#pragma unroll
                for (int off = 1; off < 16; off <<= 1) sum += __shfl_xor(sum, off);
                l_r[r] = l_r[r] * a + sum;
                alpha[r] = a;
            }
#pragma unroll
            for (int n = 0; n < 4; ++n)
#pragma unroll
                for (int r = 0; r < 4; ++r) of[n][r] *= alpha[r];

#pragma unroll
            for (int n = 0; n < 4; ++n)
#pragma unroll
                for (int r = 0; r < 4; ++r)
                    Ps[(wv * 16 + quad * 4 + r) * 72 + n * 16 + l16] = f2bf(sf[n][r]);
            __threadfence_block();

#pragma unroll
            for (int h2 = 0; h2 < 2; ++h2) {
                frag_ab pa = *(const frag_ab*)&Ps[(wv * 16 + l16) * 72 + h2 * 32 + quad * 8];
#pragma unroll
                for (int n = 0; n < 4; ++n) {
                    frag_ab vf = *(const frag_ab*)&Vs[(n * 16 + l16) * 72 + h2 * 32 + quad * 8];
                    of[n] = __builtin_amdgcn_mfma_f32_16x16x32_bf16(pa, vf, of[n], 0, 0, 0);
                }
            }
        }

#pragma unroll
        for (int r = 0; r < 4; ++r) {
            float inv = 1.f / l_r[r];
            int row = q0 + wv * 16 + quad * 4 + r;
            u16* orow = Aout + ((size_t)b * Ss + row) * Dd + h * DKk;
#pragma unroll
            for (int n = 0; n < 4; ++n) orow[n * 16 + l16] = f2bf(of[n][r] * inv);
        }
    }
}

extern "C" void kernel_launch(void* const* d_in, const int* in_sizes, int n_in,
                              void* d_out, int out_size, void* d_ws, size_t ws_size,
                              hipStream_t stream) {
    (void)in_sizes; (void)n_in; (void)out_size;
    const float* q  = (const float*)d_in[0];
    const float* k  = (const float*)d_in[1];
    const float* v  = (const float*)d_in[2];
    // d_in[3] = mask (tril causal) -- enforced analytically in attn_mfma
    const float* Wq = (const float*)d_in[4];
    const float* bq = (const float*)d_in[5];
    const float* Wk = (const float*)d_in[6];
    const float* bk = (const float*)d_in[7];
    const float* Wv = (const float*)d_in[8];
    const float* bv = (const float*)d_in[9];
    const float* Wo = (const float*)d_in[10];
    const float* bo = (const float*)d_in[11];
    float* out = (float*)d_out;

    const size_t E = (size_t)Bb * Ss * Dd;     // 4,194,304
    const size_t Wn = (size_t)Dd * Dd;         // 1,048,576
    const size_t need = (7 * E + 4 * Wn) * sizeof(u16);   // 64 MiB
    if (ws_size < need) return;
    u16* qa  = (u16*)d_ws;
    u16* ka  = qa + E;
    u16* va  = ka + E;
    u16* wqt = va + E;
    u16* wkt = wqt + Wn;
    u16* wvt = wkt + Wn;
    u16* wot = wvt + Wn;
    u16* Qh  = wot + Wn;
    u16* Kh  = Qh + E;
    u16* Vth = Kh + E;
    u16* Abf = Vth + E;

    convert_kernel<<<4096, 256, 0, stream>>>(q, k, v, Wq, Wk, Wv, Wo,
                                             qa, ka, va, wqt, wkt, wvt, wot);
    gemm_bf16<<<dim3(Dd / 64, BSn / 128, 3), 256, 0, stream>>>(
        qa, ka, va, wqt, wkt, wvt, bq, bk, bv, Qh, Kh, Vth, nullptr, 1);
    attn_mfma<<<dim3(16, Bb * Hh), 256, 0, stream>>>(Qh, Kh, Vth, Abf);
    gemm_bf16<<<dim3(Dd / 64, BSn / 128, 1), 256, 0, stream>>>(
        Abf, nullptr, nullptr, wot, nullptr, nullptr, bo, nullptr, nullptr,
        nullptr, nullptr, nullptr, out, 0);
}